// Round 2
// baseline (1259.010 us; speedup 1.0000x reference)
//
#include <hip/hip_runtime.h>
#include <stdint.h>

#define E_TOTAL   500000
#define NODE_DIM  128
#define EDGE_DIM  64
#define OUT_DIM_  128
#define LN_EPS    1e-5f
#define ROWS_PER_BLOCK 256                       // 16 waves x 16 rows
#define NTILES ((E_TOTAL + ROWS_PER_BLOCK - 1) / ROWS_PER_BLOCK)   // 1954
#define HSTRIDE 136                              // shorts per row (pad 128+8)

typedef __attribute__((ext_vector_type(8))) short  short8;
typedef __attribute__((ext_vector_type(4))) float  floatx4;
typedef __attribute__((ext_vector_type(4))) unsigned int uintx4;

union Frag { short8 s; uintx4 u; };

__device__ __forceinline__ unsigned short f2bf(float f) {
    unsigned int u = __float_as_uint(f);
    return (unsigned short)((u + 0x7FFFu + ((u >> 16) & 1u)) >> 16);  // RNE
}
__device__ __forceinline__ unsigned int pk2(float a, float b) {
    return (unsigned int)f2bf(a) | ((unsigned int)f2bf(b) << 16);
}
__device__ __forceinline__ float silu(float y) {
    return y / (1.0f + __expf(-y));
}

// LDS: wf 80*1024 = 81920 B, hstage 16*2176*2 = 69632 B, pl 2048 B -> 153600 B
// -> 1 block/CU, 16 waves/CU = 4 waves/SIMD (VGPR capped at 128 by bounds).
__launch_bounds__(1024, 1)
__global__ void edge_mlp_kernel(
    const float* __restrict__ src,   // E x 128
    const float* __restrict__ edg,   // E x 64
    const float* __restrict__ W1,    // 192 x 128 (K x N)
    const float* __restrict__ b1,    // 128
    const float* __restrict__ gam,   // 128
    const float* __restrict__ bet,   // 128
    const float* __restrict__ W2,    // 128 x 128 (K x N)
    const float* __restrict__ b2,    // 128
    float* __restrict__ out)         // E x 128
{
    // frags 0..47: W1 (s=f>>3, t=f&7); frags 48..79: W2 (s2=(f-48)>>3, t=(f-48)&7)
    __shared__ uintx4 wf[80 * 64];
    __shared__ __align__(16) unsigned short hstage[16 * 16 * HSTRIDE];
    __shared__ float pl[512];        // b1 | gamma | beta | b2

    const int tid  = threadIdx.x;
    const int lane = tid & 63;
    const int wave = tid >> 6;
    const int quad = lane >> 4;
    const int l15  = lane & 15;

    // ---- stage W1+W2 as bf16 fragments (lane holds W[k0+j][t*16+l15], j=0..7,
    //      k0 = s*32 + quad*8). Same packing serves as MFMA A-operand of W^T.
    #pragma unroll
    for (int i = 0; i < 5; ++i) {
        int f = wave + 16 * i;
        const float* base = (f < 48) ? W1 : W2;
        int g = (f < 48) ? f : (f - 48);
        int s = g >> 3, t = g & 7;
        const float* wp = base + (size_t)(s * 32 + quad * 8) * OUT_DIM_ + t * 16 + l15;
        uintx4 v;
        v.x = pk2(wp[0],            wp[OUT_DIM_]);
        v.y = pk2(wp[2 * OUT_DIM_], wp[3 * OUT_DIM_]);
        v.z = pk2(wp[4 * OUT_DIM_], wp[5 * OUT_DIM_]);
        v.w = pk2(wp[6 * OUT_DIM_], wp[7 * OUT_DIM_]);
        wf[f * 64 + lane] = v;
    }
    if (tid < 512) {
        int w = tid >> 7, o = tid & 127;
        pl[tid] = (w == 0) ? b1[o] : (w == 1) ? gam[o] : (w == 2) ? bet[o] : b2[o];
    }
    __syncthreads();

    const floatx4* pl4 = (const floatx4*)pl;
    const int hs_base = wave * (16 * HSTRIDE);

    for (int tile = blockIdx.x; tile < NTILES; tile += gridDim.x) {
        const int ra  = tile * ROWS_PER_BLOCK + wave * 16 + l15;   // this lane's row
        const int rca = ra < E_TOTAL ? ra : (E_TOTAL - 1);
        const bool ok = ra < E_TOTAL;
        const float* sp = src + (size_t)rca * NODE_DIM + quad * 8;
        const float* ep = edg + (size_t)rca * EDGE_DIM + quad * 8;

        floatx4 acc[8];
        #pragma unroll
        for (int t = 0; t < 8; ++t) acc[t] = (floatx4)(0.0f);

        // ---- GEMM1 (swapped: A = W1^T frag, B = X^T frag) -> acc = h^T tiles
        //      D row (quad*4+j) = n_local, D col (l15) = m
        #pragma unroll
        for (int s = 0; s < 6; ++s) {
            const float* p = (s < 4) ? (sp + s * 32) : (ep + (s - 4) * 32);
            floatx4 x0 = *(const floatx4*)(p);
            floatx4 x1 = *(const floatx4*)(p + 4);
            Frag a;
            a.u.x = pk2(x0.x, x0.y);
            a.u.y = pk2(x0.z, x0.w);
            a.u.z = pk2(x1.x, x1.y);
            a.u.w = pk2(x1.z, x1.w);
            #pragma unroll
            for (int t = 0; t < 8; ++t) {
                Frag w; w.u = wf[(s * 8 + t) * 64 + lane];
                acc[t] = __builtin_amdgcn_mfma_f32_16x16x32_bf16(w.s, a.s, acc[t], 0, 0, 0);
            }
        }

        // ---- + b1, LN stats: lane holds 32 features of row m=l15
        float S1 = 0.0f, S2 = 0.0f;
        #pragma unroll
        for (int t = 0; t < 8; ++t) {
            floatx4 b1v = pl4[t * 4 + quad];
            #pragma unroll
            for (int j = 0; j < 4; ++j) {
                float h = acc[t][j] + b1v[j];
                acc[t][j] = h;
                S1 += h;
                S2 += h * h;
            }
        }
        S1 += __shfl_xor(S1, 16, 64);  S2 += __shfl_xor(S2, 16, 64);
        S1 += __shfl_xor(S1, 32, 64);  S2 += __shfl_xor(S2, 32, 64);
        const float mu = S1 * (1.0f / 128.0f);
        const float rs = rsqrtf(S2 * (1.0f / 128.0f) - mu * mu + LN_EPS);

        // ---- normalize + affine + SiLU -> hstage row-major (m, k), b64 writes
        #pragma unroll
        for (int t = 0; t < 8; ++t) {
            floatx4 gv = pl4[32 + t * 4 + quad];
            floatx4 bv = pl4[64 + t * 4 + quad];
            float y0 = silu((acc[t][0] - mu) * rs * gv[0] + bv[0]);
            float y1 = silu((acc[t][1] - mu) * rs * gv[1] + bv[1]);
            float y2 = silu((acc[t][2] - mu) * rs * gv[2] + bv[2]);
            float y3 = silu((acc[t][3] - mu) * rs * gv[3] + bv[3]);
            unsigned long long pk = (unsigned long long)pk2(y0, y1)
                                  | ((unsigned long long)pk2(y2, y3) << 32);
            *(unsigned long long*)&hstage[hs_base + l15 * HSTRIDE + t * 16 + quad * 4] = pk;
        }

        // ---- GEMM2 (A = W2^T frag from LDS, B = hs^T frag from hstage)
        #pragma unroll
        for (int t = 0; t < 8; ++t) acc[t] = (floatx4)(0.0f);
        #pragma unroll
        for (int s2 = 0; s2 < 4; ++s2) {
            Frag b;
            b.u = *(const uintx4*)&hstage[hs_base + l15 * HSTRIDE + s2 * 32 + quad * 8];
            #pragma unroll
            for (int t = 0; t < 8; ++t) {
                Frag w; w.u = wf[(48 + s2 * 8 + t) * 64 + lane];
                acc[t] = __builtin_amdgcn_mfma_f32_16x16x32_bf16(w.s, b.s, acc[t], 0, 0, 0);
            }
        }

        // ---- + b2, SiLU, float4 nontemporal stores (row = l15)
        float* op = out + (size_t)rca * OUT_DIM_ + quad * 4;
        #pragma unroll
        for (int t = 0; t < 8; ++t) {
            floatx4 b2v = pl4[96 + t * 4 + quad];
            floatx4 v;
            v.x = silu(acc[t][0] + b2v[0]);
            v.y = silu(acc[t][1] + b2v[1]);
            v.z = silu(acc[t][2] + b2v[2]);
            v.w = silu(acc[t][3] + b2v[3]);
            if (ok) __builtin_nontemporal_store(v, (floatx4*)(op + t * 16));
        }
    }
}

extern "C" void kernel_launch(void* const* d_in, const int* in_sizes, int n_in,
                              void* d_out, int out_size, void* d_ws, size_t ws_size,
                              hipStream_t stream) {
    const float* src = (const float*)d_in[0];
    const float* edg = (const float*)d_in[1];
    const float* W1  = (const float*)d_in[2];
    const float* b1  = (const float*)d_in[3];
    const float* gam = (const float*)d_in[4];
    const float* bet = (const float*)d_in[5];
    const float* W2  = (const float*)d_in[6];
    const float* b2  = (const float*)d_in[7];
    float* out = (float*)d_out;

    edge_mlp_kernel<<<256, 1024, 0, stream>>>(src, edg, W1, b1, gam, bet, W2, b2, out);
}